// Round 5
// baseline (155.026 us; speedup 1.0000x reference)
//
#include <hip/hip_runtime.h>
#include <cmath>

// Router: R=4096 nodes, D=64, DEG=6 edges per destination (contiguous:
// dst_idx[e] = e/6). One block per destination node; block-local 6-way
// softmax; big weight tensors streamed once, coalesced float4.
// v5 = v1 with ONE change: edge loop processes 2 edges per iteration
// (16 float4 in flight per thread instead of 8) to raise MLP.
// History: v1=153.2µs (5.7 TB/s). v2 barrier-restructure=160. v3 nt-loads=261
// (VGPR=32, load stream serialized — BW tracks in-flight loads). v4=v1 repro.

#define R_N   4096
#define D_N   64
#define DEG_N 6

__device__ __forceinline__ float softplusf(float x) {
    return (x > 20.0f) ? x : log1pf(expf(x));
}

__global__ __launch_bounds__(256) void router_kernel(
    const float* __restrict__ H,        // [R,64]
    const int*   __restrict__ mask,     // [R]
    const float* __restrict__ coords,   // [R,2]
    const float* __restrict__ W_edge,   // [E,64,64]
    const float* __restrict__ key_W,    // [E,64,64]
    const float* __restrict__ rawP,     // [E,64]
    const float* __restrict__ query_W,  // [R,64,64]
    const float* __restrict__ W_reg,    // [8,2]
    const float* __restrict__ beta_cos, // [8]
    const float* __restrict__ beta_sin, // [8]
    const int*   __restrict__ src_idx,  // [E]
    float*       __restrict__ out)      // [R,64]
{
    const int r    = blockIdx.x;
    const int t    = threadIdx.x;
    const int wave = t >> 6;
    const int lane = t & 63;

    __shared__ float hdst[64];
    __shared__ float hsrc[DEG_N][64];
    __shared__ float qv[64];
    __shared__ float msg[DEG_N][64];
    __shared__ float sc_part[DEG_N][4];
    __shared__ float mahs[DEG_N];
    __shared__ float bfr[DEG_N];
    __shared__ int   smask[DEG_N];
    __shared__ float wgt[DEG_N];

    // ---------- load phase ----------
    if (t < 64) hdst[t] = H[(size_t)r * 64 + t];
    for (int idx = t; idx < DEG_N * 64; idx += 256) {
        int k = idx >> 6, d = idx & 63;
        int s = src_idx[r * DEG_N + k];
        hsrc[k][d] = H[(size_t)s * 64 + d];
    }
    if (t < DEG_N) {
        int s = src_idx[r * DEG_N + t];
        smask[t] = (mask[s] != 0);
        float dx = coords[2 * r + 0] - coords[2 * s + 0];
        float dy = coords[2 * r + 1] - coords[2 * s + 1];
        float b = 0.f;
        #pragma unroll
        for (int m = 0; m < 8; ++m) {
            float S = dx * W_reg[2 * m + 0] + dy * W_reg[2 * m + 1];
            b += cosf(S) * beta_cos[m] + sinf(S) * beta_sin[m];
        }
        // fb_scale = 1/sqrt(8); msg *= (1 + 0.1*b*fb_scale)
        bfr[t] = 1.0f + 0.1f * b * 0.35355339059327373f;
    }
    __syncthreads();

    const int row = t >> 2;          // output row this thread contributes to
    const int c0  = (t & 3) * 16;    // column strip start

    // ---------- query matvec: qv = query_W[r] @ hdst ----------
    {
        const float4* wp = reinterpret_cast<const float4*>(
            query_W + (size_t)r * 4096 + (size_t)t * 16);
        float4 w0 = wp[0], w1 = wp[1], w2 = wp[2], w3 = wp[3];
        const float* x = hdst + c0;
        float a = w0.x*x[0]  + w0.y*x[1]  + w0.z*x[2]  + w0.w*x[3]
                + w1.x*x[4]  + w1.y*x[5]  + w1.z*x[6]  + w1.w*x[7]
                + w2.x*x[8]  + w2.y*x[9]  + w2.z*x[10] + w2.w*x[11]
                + w3.x*x[12] + w3.y*x[13] + w3.z*x[14] + w3.w*x[15];
        a += __shfl_xor(a, 1);
        a += __shfl_xor(a, 2);
        if ((t & 3) == 0) qv[row] = a;
    }
    __syncthreads();

    const float qrow = qv[row];

    // ---------- per-edge matvecs: 2 edges per iteration (MLP x2) ----------
    for (int k = 0; k < DEG_N; k += 2) {
        const size_t e0 = (size_t)r * DEG_N + k;
        const size_t e1 = e0 + 1;
        const float4* wp0 = reinterpret_cast<const float4*>(
            W_edge + e0 * 4096 + (size_t)t * 16);
        const float4* kp0 = reinterpret_cast<const float4*>(
            key_W + e0 * 4096 + (size_t)t * 16);
        const float4* wp1 = reinterpret_cast<const float4*>(
            W_edge + e1 * 4096 + (size_t)t * 16);
        const float4* kp1 = reinterpret_cast<const float4*>(
            key_W + e1 * 4096 + (size_t)t * 16);

        float4 a0 = wp0[0], a1 = wp0[1], a2 = wp0[2], a3 = wp0[3];
        float4 b0 = kp0[0], b1 = kp0[1], b2 = kp0[2], b3 = kp0[3];
        float4 c0v = wp1[0], c1 = wp1[1], c2 = wp1[2], c3 = wp1[3];
        float4 d0 = kp1[0], d1 = kp1[1], d2 = kp1[2], d3 = kp1[3];

        const float* x0 = hsrc[k] + c0;
        const float* x1 = hsrc[k + 1] + c0;

        float am0 = a0.x*x0[0]  + a0.y*x0[1]  + a0.z*x0[2]  + a0.w*x0[3]
                  + a1.x*x0[4]  + a1.y*x0[5]  + a1.z*x0[6]  + a1.w*x0[7]
                  + a2.x*x0[8]  + a2.y*x0[9]  + a2.z*x0[10] + a2.w*x0[11]
                  + a3.x*x0[12] + a3.y*x0[13] + a3.z*x0[14] + a3.w*x0[15];
        float ak0 = b0.x*x0[0]  + b0.y*x0[1]  + b0.z*x0[2]  + b0.w*x0[3]
                  + b1.x*x0[4]  + b1.y*x0[5]  + b1.z*x0[6]  + b1.w*x0[7]
                  + b2.x*x0[8]  + b2.y*x0[9]  + b2.z*x0[10] + b2.w*x0[11]
                  + b3.x*x0[12] + b3.y*x0[13] + b3.z*x0[14] + b3.w*x0[15];
        float am1 = c0v.x*x1[0] + c0v.y*x1[1] + c0v.z*x1[2] + c0v.w*x1[3]
                  + c1.x*x1[4]  + c1.y*x1[5]  + c1.z*x1[6]  + c1.w*x1[7]
                  + c2.x*x1[8]  + c2.y*x1[9]  + c2.z*x1[10] + c2.w*x1[11]
                  + c3.x*x1[12] + c3.y*x1[13] + c3.z*x1[14] + c3.w*x1[15];
        float ak1 = d0.x*x1[0]  + d0.y*x1[1]  + d0.z*x1[2]  + d0.w*x1[3]
                  + d1.x*x1[4]  + d1.y*x1[5]  + d1.z*x1[6]  + d1.w*x1[7]
                  + d2.x*x1[8]  + d2.y*x1[9]  + d2.z*x1[10] + d2.w*x1[11]
                  + d3.x*x1[12] + d3.y*x1[13] + d3.z*x1[14] + d3.w*x1[15];

        am0 += __shfl_xor(am0, 1);
        am0 += __shfl_xor(am0, 2);
        am1 += __shfl_xor(am1, 1);
        am1 += __shfl_xor(am1, 2);
        if ((t & 3) == 0) {
            msg[k][row]     = am0 * bfr[k];
            msg[k + 1][row] = am1 * bfr[k + 1];
        }

        float s0 = ak0 * qrow;
        float s1 = ak1 * qrow;
        #pragma unroll
        for (int s2 = 1; s2 < 64; s2 <<= 1) {
            s0 += __shfl_xor(s0, s2);
            s1 += __shfl_xor(s1, s2);
        }
        if (lane == 0) {
            sc_part[k][wave]     = s0;
            sc_part[k + 1][wave] = s1;
        }
    }
    __syncthreads();

    // ---------- Mahalanobis term: one wave per edge ----------
    for (int k = wave; k < DEG_N; k += 4) {
        float m = msg[k][lane] - hdst[lane];
        float p = softplusf(rawP[((size_t)r * DEG_N + k) * 64 + lane]);
        float c = m * m * p;
        #pragma unroll
        for (int s2 = 1; s2 < 64; s2 <<= 1) c += __shfl_xor(c, s2);
        if (lane == 0) mahs[k] = c;
    }
    __syncthreads();

    // ---------- 6-way stable softmax (single thread) ----------
    if (t == 0) {
        float lw[DEG_N];
        float maxl = -INFINITY;
        #pragma unroll
        for (int k = 0; k < DEG_N; ++k) {
            float sc = (sc_part[k][0] + sc_part[k][1] +
                        sc_part[k][2] + sc_part[k][3]) * 0.125f; // 1/sqrt(64)
            float mh = fminf(mahs[k], 160.0f);                    // MAX_EXP/0.5
            float l  = smask[k] ? (sc - 0.5f * mh) : -INFINITY;
            lw[k] = l;
            maxl  = fmaxf(maxl, l);
        }
        float s = 0.f;
        #pragma unroll
        for (int k = 0; k < DEG_N; ++k)
            s += smask[k] ? expf(lw[k] - maxl) : 0.f;
        float logZ = maxl + logf(fmaxf(s, 1e-12f));
        #pragma unroll
        for (int k = 0; k < DEG_N; ++k)
            wgt[k] = smask[k] ? expf(lw[k] - logZ) : 0.f;
    }
    __syncthreads();

    // ---------- weighted scatter (block-local) ----------
    if (t < 64) {
        float o = 0.f;
        #pragma unroll
        for (int k = 0; k < DEG_N; ++k) o += wgt[k] * msg[k][t];
        out[(size_t)r * 64 + t] = o;
    }
}

extern "C" void kernel_launch(void* const* d_in, const int* in_sizes, int n_in,
                              void* d_out, int out_size, void* d_ws, size_t ws_size,
                              hipStream_t stream) {
    const float* H        = (const float*)d_in[0];
    const int*   mask     = (const int*)  d_in[1];
    const float* coords   = (const float*)d_in[2];
    const float* W_edge   = (const float*)d_in[3];
    const float* key_W    = (const float*)d_in[4];
    const float* rawP     = (const float*)d_in[5];
    const float* query_W  = (const float*)d_in[6];
    const float* W_reg    = (const float*)d_in[7];
    const float* bcos     = (const float*)d_in[8];
    const float* bsin     = (const float*)d_in[9];
    const int*   src      = (const int*)  d_in[10];
    // d_in[11] = dst_idx: structurally dst[e] = e/6, handled by block id

    float* out = (float*)d_out;
    router_kernel<<<R_N, 256, 0, stream>>>(
        H, mask, coords, W_edge, key_W, rawP, query_W,
        W_reg, bcos, bsin, src, out);
}

// Round 6
// 152.998 us; speedup vs baseline: 1.0133x; 1.0133x over previous
//
#include <hip/hip_runtime.h>
#include <cmath>

// Router: R=4096 nodes, D=64, DEG=6 edges per destination (contiguous:
// dst_idx[e] = e/6). One block per destination node; block-local 6-way
// softmax; all big weight tensors (W_edge, key_W, query_W) streamed once,
// coalesced float4.
// FINAL (v1 structure — best measured: 153.2/153.3 µs, 5.7 TB/s logical
// = 90% of achievable copy BW). Tested and rejected: v2 barrier
// restructure (160), v3 nontemporal loads (261, VGPR=32 serialized the
// load stream), v5 2-edge MLP unroll (155, neutral -> MLP not limiting).
// Memory-bound at the streaming ceiling; do not "improve" load scheduling.

#define R_N   4096
#define D_N   64
#define DEG_N 6

__device__ __forceinline__ float softplusf(float x) {
    // stable softplus; raw_P is ~0 here but keep it general
    return (x > 20.0f) ? x : log1pf(expf(x));
}

__global__ __launch_bounds__(256) void router_kernel(
    const float* __restrict__ H,        // [R,64]
    const int*   __restrict__ mask,     // [R]
    const float* __restrict__ coords,   // [R,2]
    const float* __restrict__ W_edge,   // [E,64,64]
    const float* __restrict__ key_W,    // [E,64,64]
    const float* __restrict__ rawP,     // [E,64]
    const float* __restrict__ query_W,  // [R,64,64]
    const float* __restrict__ W_reg,    // [8,2]
    const float* __restrict__ beta_cos, // [8]
    const float* __restrict__ beta_sin, // [8]
    const int*   __restrict__ src_idx,  // [E]
    float*       __restrict__ out)      // [R,64]
{
    const int r    = blockIdx.x;
    const int t    = threadIdx.x;
    const int wave = t >> 6;
    const int lane = t & 63;

    __shared__ float hdst[64];
    __shared__ float hsrc[DEG_N][64];
    __shared__ float qv[64];
    __shared__ float msg[DEG_N][64];
    __shared__ float sc_part[DEG_N][4];
    __shared__ float mahs[DEG_N];
    __shared__ float bfr[DEG_N];
    __shared__ int   smask[DEG_N];
    __shared__ float wgt[DEG_N];

    // ---------- load phase ----------
    if (t < 64) hdst[t] = H[(size_t)r * 64 + t];
    for (int idx = t; idx < DEG_N * 64; idx += 256) {
        int k = idx >> 6, d = idx & 63;
        int s = src_idx[r * DEG_N + k];
        hsrc[k][d] = H[(size_t)s * 64 + d];
    }
    if (t < DEG_N) {
        int s = src_idx[r * DEG_N + t];
        smask[t] = (mask[s] != 0);
        float dx = coords[2 * r + 0] - coords[2 * s + 0];
        float dy = coords[2 * r + 1] - coords[2 * s + 1];
        float b = 0.f;
        #pragma unroll
        for (int m = 0; m < 8; ++m) {
            float S = dx * W_reg[2 * m + 0] + dy * W_reg[2 * m + 1];
            b += cosf(S) * beta_cos[m] + sinf(S) * beta_sin[m];
        }
        // fb_scale = 1/sqrt(8); msg *= (1 + 0.1*b*fb_scale)
        bfr[t] = 1.0f + 0.1f * b * 0.35355339059327373f;
    }
    __syncthreads();

    const int row = t >> 2;          // output row this thread contributes to
    const int c0  = (t & 3) * 16;    // column strip start

    // ---------- query matvec: qv = query_W[r] @ hdst ----------
    {
        const float4* wp = reinterpret_cast<const float4*>(
            query_W + (size_t)r * 4096 + (size_t)t * 16);
        float4 w0 = wp[0], w1 = wp[1], w2 = wp[2], w3 = wp[3];
        const float* x = hdst + c0;
        float a = w0.x*x[0]  + w0.y*x[1]  + w0.z*x[2]  + w0.w*x[3]
                + w1.x*x[4]  + w1.y*x[5]  + w1.z*x[6]  + w1.w*x[7]
                + w2.x*x[8]  + w2.y*x[9]  + w2.z*x[10] + w2.w*x[11]
                + w3.x*x[12] + w3.y*x[13] + w3.z*x[14] + w3.w*x[15];
        a += __shfl_xor(a, 1);
        a += __shfl_xor(a, 2);
        if ((t & 3) == 0) qv[row] = a;
    }
    __syncthreads();

    const float qrow = qv[row];

    // ---------- per-edge matvecs: msg and score ----------
    for (int k = 0; k < DEG_N; ++k) {
        const size_t e = (size_t)r * DEG_N + k;
        const float4* wp = reinterpret_cast<const float4*>(
            W_edge + e * 4096 + (size_t)t * 16);
        const float4* kp = reinterpret_cast<const float4*>(
            key_W + e * 4096 + (size_t)t * 16);
        float4 a0 = wp[0], a1 = wp[1], a2 = wp[2], a3 = wp[3];
        float4 b0 = kp[0], b1 = kp[1], b2 = kp[2], b3 = kp[3];
        const float* x = hsrc[k] + c0;

        float am = a0.x*x[0]  + a0.y*x[1]  + a0.z*x[2]  + a0.w*x[3]
                 + a1.x*x[4]  + a1.y*x[5]  + a1.z*x[6]  + a1.w*x[7]
                 + a2.x*x[8]  + a2.y*x[9]  + a2.z*x[10] + a2.w*x[11]
                 + a3.x*x[12] + a3.y*x[13] + a3.z*x[14] + a3.w*x[15];
        float ak = b0.x*x[0]  + b0.y*x[1]  + b0.z*x[2]  + b0.w*x[3]
                 + b1.x*x[4]  + b1.y*x[5]  + b1.z*x[6]  + b1.w*x[7]
                 + b2.x*x[8]  + b2.y*x[9]  + b2.z*x[10] + b2.w*x[11]
                 + b3.x*x[12] + b3.y*x[13] + b3.z*x[14] + b3.w*x[15];

        // message: reduce 4-lane column strips -> full row dot
        am += __shfl_xor(am, 1);
        am += __shfl_xor(am, 2);
        if ((t & 3) == 0) msg[k][row] = am * bfr[k];

        // score partial: q[dst][row] * K[row] summed over everything
        float c = ak * qrow;
        #pragma unroll
        for (int s2 = 1; s2 < 64; s2 <<= 1) c += __shfl_xor(c, s2);
        if (lane == 0) sc_part[k][wave] = c;
    }
    __syncthreads();

    // ---------- Mahalanobis term: one wave per edge ----------
    for (int k = wave; k < DEG_N; k += 4) {
        float m = msg[k][lane] - hdst[lane];
        float p = softplusf(rawP[((size_t)r * DEG_N + k) * 64 + lane]);
        float c = m * m * p;
        #pragma unroll
        for (int s2 = 1; s2 < 64; s2 <<= 1) c += __shfl_xor(c, s2);
        if (lane == 0) mahs[k] = c;
    }
    __syncthreads();

    // ---------- 6-way stable softmax (single thread) ----------
    if (t == 0) {
        float lw[DEG_N];
        float maxl = -INFINITY;
        #pragma unroll
        for (int k = 0; k < DEG_N; ++k) {
            float sc = (sc_part[k][0] + sc_part[k][1] +
                        sc_part[k][2] + sc_part[k][3]) * 0.125f; // 1/sqrt(64)
            float mh = fminf(mahs[k], 160.0f);                    // MAX_EXP/0.5
            float l  = smask[k] ? (sc - 0.5f * mh) : -INFINITY;
            lw[k] = l;
            maxl  = fmaxf(maxl, l);
        }
        float s = 0.f;
        #pragma unroll
        for (int k = 0; k < DEG_N; ++k)
            s += smask[k] ? expf(lw[k] - maxl) : 0.f;
        float logZ = maxl + logf(fmaxf(s, 1e-12f));
        #pragma unroll
        for (int k = 0; k < DEG_N; ++k)
            wgt[k] = smask[k] ? expf(lw[k] - logZ) : 0.f;
    }
    __syncthreads();

    // ---------- weighted scatter (block-local) ----------
    if (t < 64) {
        float o = 0.f;
        #pragma unroll
        for (int k = 0; k < DEG_N; ++k) o += wgt[k] * msg[k][t];
        out[(size_t)r * 64 + t] = o;
    }
}

extern "C" void kernel_launch(void* const* d_in, const int* in_sizes, int n_in,
                              void* d_out, int out_size, void* d_ws, size_t ws_size,
                              hipStream_t stream) {
    const float* H        = (const float*)d_in[0];
    const int*   mask     = (const int*)  d_in[1];
    const float* coords   = (const float*)d_in[2];
    const float* W_edge   = (const float*)d_in[3];
    const float* key_W    = (const float*)d_in[4];
    const float* rawP     = (const float*)d_in[5];
    const float* query_W  = (const float*)d_in[6];
    const float* W_reg    = (const float*)d_in[7];
    const float* bcos     = (const float*)d_in[8];
    const float* bsin     = (const float*)d_in[9];
    const int*   src      = (const int*)  d_in[10];
    // d_in[11] = dst_idx: structurally dst[e] = e/6, handled by block id

    float* out = (float*)d_out;
    router_kernel<<<R_N, 256, 0, stream>>>(
        H, mask, coords, W_edge, key_W, rawP, query_W,
        W_reg, bcos, bsin, src, out);
}